// Round 1
// baseline (1564.240 us; speedup 1.0000x reference)
//
#include <hip/hip_runtime.h>

// Problem constants (verified against in_sizes at runtime where cheap)
#define FDIM 64

static inline size_t align_up(size_t v) { return (v + 255) & ~(size_t)255; }

// ---------------- CSR build ----------------

__global__ void k_count(const int* __restrict__ dst, int* __restrict__ deg, int E) {
    int e = blockIdx.x * blockDim.x + threadIdx.x;
    if (e < E) atomicAdd(&deg[dst[e]], 1);
}

// block sums over 1024-element chunks
__global__ void k_scan1(const int* __restrict__ deg, int* __restrict__ bsum, int n) {
    __shared__ int sh[256];
    int base = blockIdx.x * 1024;
    int t = threadIdx.x;
    int s = 0;
#pragma unroll
    for (int j = 0; j < 4; j++) {
        int i = base + t * 4 + j;
        s += (i < n) ? deg[i] : 0;
    }
    sh[t] = s;
    __syncthreads();
    for (int off = 128; off > 0; off >>= 1) {
        if (t < off) sh[t] += sh[t + off];
        __syncthreads();
    }
    if (t == 0) bsum[blockIdx.x] = sh[0];
}

// exclusive scan of block sums (nb <= 256), also write rowstart[n] = E
__global__ void k_scan2(int* __restrict__ bsum, int nb, int* __restrict__ rowstart, int n, int E) {
    if (threadIdx.x == 0) {
        int acc = 0;
        for (int i = 0; i < nb; i++) {
            int v = bsum[i];
            bsum[i] = acc;
            acc += v;
        }
        rowstart[n] = E;
    }
}

__global__ void k_scan3(const int* __restrict__ deg, const int* __restrict__ bsum,
                        int* __restrict__ rowstart, int n) {
    __shared__ int sh[256];
    int base = blockIdx.x * 1024;
    int t = threadIdx.x;
    int v[4];
    int s = 0;
#pragma unroll
    for (int j = 0; j < 4; j++) {
        int i = base + t * 4 + j;
        v[j] = (i < n) ? deg[i] : 0;
        s += v[j];
    }
    sh[t] = s;
    __syncthreads();
    // Hillis-Steele inclusive scan over 256 thread sums
    for (int off = 1; off < 256; off <<= 1) {
        int add = (t >= off) ? sh[t - off] : 0;
        __syncthreads();
        sh[t] += add;
        __syncthreads();
    }
    int excl = (t == 0 ? 0 : sh[t - 1]) + bsum[blockIdx.x];
#pragma unroll
    for (int j = 0; j < 4; j++) {
        int i = base + t * 4 + j;
        if (i < n) {
            rowstart[i] = excl;
            excl += v[j];
        }
    }
}

__global__ void k_fill(const int* __restrict__ src, const int* __restrict__ dst,
                       const int* __restrict__ rowstart, int* __restrict__ cursor,
                       int* __restrict__ adj, int E) {
    int e = blockIdx.x * blockDim.x + threadIdx.x;
    if (e < E) {
        int d = dst[e];
        int pos = rowstart[d] + atomicAdd(&cursor[d], 1);
        adj[pos] = src[e];
    }
}

// ---------------- aggregation: wave per node, lane = feature ----------------

__global__ __launch_bounds__(256) void k_agg(const float* __restrict__ h,
                                             const int* __restrict__ rowstart,
                                             const int* __restrict__ adj,
                                             float* __restrict__ agg, int n) {
    int wave = (blockIdx.x * 256 + threadIdx.x) >> 6;
    int lane = threadIdx.x & 63;
    if (wave >= n) return;
    int s0 = rowstart[wave];
    int s1 = rowstart[wave + 1];
    float acc = 0.f;
    for (int j = s0; j < s1; j++) {
        int srcn = adj[j];
        acc += h[(long)srcn * FDIM + lane];
    }
    agg[(long)wave * FDIM + lane] = acc;
}

// ---------------- fused dual GEMM + bias + optional PReLU ----------------
// Y[n,:] = prelu( A[n,:] @ Wr + X[n,:] @ Wo + b )

__global__ __launch_bounds__(256) void k_gemm(const float* __restrict__ A,
                                              const float* __restrict__ X,
                                              const float* __restrict__ Wr,
                                              const float* __restrict__ Wo,
                                              const float* __restrict__ bias,
                                              const float* __restrict__ slope_p,
                                              float* __restrict__ Y, int n, int do_prelu) {
    int node = blockIdx.x * blockDim.x + threadIdx.x;
    if (node >= n) return;
    float a[FDIM], x[FDIM];
    const float4* pa = (const float4*)(A + (long)node * FDIM);
    const float4* px = (const float4*)(X + (long)node * FDIM);
#pragma unroll
    for (int i = 0; i < FDIM / 4; i++) {
        float4 v = pa[i];
        a[4 * i] = v.x; a[4 * i + 1] = v.y; a[4 * i + 2] = v.z; a[4 * i + 3] = v.w;
    }
#pragma unroll
    for (int i = 0; i < FDIM / 4; i++) {
        float4 v = px[i];
        x[4 * i] = v.x; x[4 * i + 1] = v.y; x[4 * i + 2] = v.z; x[4 * i + 3] = v.w;
    }
    float slope = do_prelu ? slope_p[0] : 0.f;
    float4* out4 = (float4*)(Y + (long)node * FDIM);
    for (int f0 = 0; f0 < FDIM; f0 += 4) {
        float acc0 = bias[f0 + 0];
        float acc1 = bias[f0 + 1];
        float acc2 = bias[f0 + 2];
        float acc3 = bias[f0 + 3];
#pragma unroll
        for (int k = 0; k < FDIM; k++) {
            float ak = a[k];
            acc0 += ak * Wr[k * FDIM + f0 + 0];
            acc1 += ak * Wr[k * FDIM + f0 + 1];
            acc2 += ak * Wr[k * FDIM + f0 + 2];
            acc3 += ak * Wr[k * FDIM + f0 + 3];
        }
#pragma unroll
        for (int k = 0; k < FDIM; k++) {
            float xk = x[k];
            acc0 += xk * Wo[k * FDIM + f0 + 0];
            acc1 += xk * Wo[k * FDIM + f0 + 1];
            acc2 += xk * Wo[k * FDIM + f0 + 2];
            acc3 += xk * Wo[k * FDIM + f0 + 3];
        }
        if (do_prelu) {
            acc0 = acc0 >= 0.f ? acc0 : slope * acc0;
            acc1 = acc1 >= 0.f ? acc1 : slope * acc1;
            acc2 = acc2 >= 0.f ? acc2 : slope * acc2;
            acc3 = acc3 >= 0.f ? acc3 : slope * acc3;
        }
        float4 o;
        o.x = acc0; o.y = acc1; o.z = acc2; o.w = acc3;
        out4[f0 / 4] = o;
    }
}

// ---------------- global mean pool (atomics) ----------------

__global__ void k_pool(const float* __restrict__ h, const int* __restrict__ batch,
                       float* __restrict__ sums, float* __restrict__ cnt, int n) {
    int id = blockIdx.x * blockDim.x + threadIdx.x;
    if (id >= n * FDIM) return;
    int node = id >> 6;
    int f = id & 63;
    int g = batch[node];
    atomicAdd(&sums[g * FDIM + f], h[id]);
    if (f == 0) atomicAdd(&cnt[g], 1.0f);
}

// ---------------- head: pooled @ W0 + b0, @ W1 + b1 ----------------

__global__ void k_head(const float* __restrict__ sums, const float* __restrict__ cnt,
                       const float* __restrict__ W0, const float* __restrict__ b0,
                       const float* __restrict__ W1, const float* __restrict__ b1,
                       float* __restrict__ out, int G, int OUT) {
    int g = threadIdx.x;
    if (g >= G) return;
    float c = cnt[g];
    if (c < 1.f) c = 1.f;
    float p[FDIM];
#pragma unroll
    for (int k = 0; k < FDIM; k++) p[k] = sums[g * FDIM + k] / c;
    float hid[FDIM];
    for (int f = 0; f < FDIM; f++) {
        float acc = b0[f];
#pragma unroll
        for (int k = 0; k < FDIM; k++) acc += p[k] * W0[k * FDIM + f];
        hid[f] = acc;
    }
    for (int o = 0; o < OUT; o++) {
        float acc = b1[o];
#pragma unroll
        for (int f = 0; f < FDIM; f++) acc += hid[f] * W1[f * OUT + o];
        out[g * OUT + o] = acc;
    }
}

extern "C" void kernel_launch(void* const* d_in, const int* in_sizes, int n_in,
                              void* d_out, int out_size, void* d_ws, size_t ws_size,
                              hipStream_t stream) {
    const float* x     = (const float*)d_in[0];
    const int*   ei    = (const int*)d_in[1];
    const int*   batch = (const int*)d_in[2];
    const float* W1r = (const float*)d_in[3];
    const float* b1  = (const float*)d_in[4];
    const float* W1o = (const float*)d_in[5];
    const float* W2r = (const float*)d_in[6];
    const float* b2  = (const float*)d_in[7];
    const float* W2o = (const float*)d_in[8];
    const float* W3r = (const float*)d_in[9];
    const float* b3  = (const float*)d_in[10];
    const float* W3o = (const float*)d_in[11];
    const float* a1  = (const float*)d_in[12];
    const float* a2  = (const float*)d_in[13];
    const float* Wl0 = (const float*)d_in[14];
    const float* bl0 = (const float*)d_in[15];
    const float* Wl1 = (const float*)d_in[16];
    const float* bl1 = (const float*)d_in[17];

    int N = in_sizes[0] / FDIM;
    int E = in_sizes[1] / 2;
    int OUT = in_sizes[17];
    int G = out_size / OUT;

    const int* src = ei;
    const int* dst = ei + E;

    // workspace layout
    char* w = (char*)d_ws;
    int* rowstart = (int*)w;            w += align_up((size_t)(N + 1) * 4);
    int* deg      = (int*)w;            w += align_up((size_t)N * 4);
    int* cursor   = (int*)w;            w += align_up((size_t)N * 4);
    int* bsum     = (int*)w;            w += align_up(1024 * 4);
    int* adj      = (int*)w;            w += align_up((size_t)E * 4);
    float* aggbuf = (float*)w;          w += align_up((size_t)N * FDIM * 4);
    float* h1     = (float*)w;          w += align_up((size_t)N * FDIM * 4);
    float* h2     = (float*)w;          w += align_up((size_t)N * FDIM * 4);
    float* sums   = (float*)w;          w += align_up((size_t)G * FDIM * 4);
    float* cnt    = (float*)w;          w += align_up((size_t)G * 4);

    hipMemsetAsync(deg, 0, (size_t)N * 4, stream);
    hipMemsetAsync(cursor, 0, (size_t)N * 4, stream);
    hipMemsetAsync(sums, 0, (size_t)G * FDIM * 4, stream);
    hipMemsetAsync(cnt, 0, (size_t)G * 4, stream);

    // CSR build
    k_count<<<(E + 255) / 256, 256, 0, stream>>>(dst, deg, E);
    int NB = (N + 1023) / 1024;
    k_scan1<<<NB, 256, 0, stream>>>(deg, bsum, N);
    k_scan2<<<1, 64, 0, stream>>>(bsum, NB, rowstart, N, E);
    k_scan3<<<NB, 256, 0, stream>>>(deg, bsum, rowstart, N);
    k_fill<<<(E + 255) / 256, 256, 0, stream>>>(src, dst, rowstart, cursor, adj, E);

    int aggGrid = (N + 3) / 4;       // 4 waves (nodes) per 256-thread block
    int gemmGrid = (N + 255) / 256;

    // layer 1: in = x
    k_agg<<<aggGrid, 256, 0, stream>>>(x, rowstart, adj, aggbuf, N);
    k_gemm<<<gemmGrid, 256, 0, stream>>>(aggbuf, x, W1r, W1o, b1, a1, h1, N, 1);
    // layer 2
    k_agg<<<aggGrid, 256, 0, stream>>>(h1, rowstart, adj, aggbuf, N);
    k_gemm<<<gemmGrid, 256, 0, stream>>>(aggbuf, h1, W2r, W2o, b2, a2, h2, N, 1);
    // layer 3 (no PReLU) -> reuse h1 as output
    k_agg<<<aggGrid, 256, 0, stream>>>(h2, rowstart, adj, aggbuf, N);
    k_gemm<<<gemmGrid, 256, 0, stream>>>(aggbuf, h2, W3r, W3o, b3, nullptr, h1, N, 0);

    // mean pool + head
    k_pool<<<((size_t)N * FDIM + 255) / 256, 256, 0, stream>>>(h1, batch, sums, cnt, N);
    k_head<<<1, 64, 0, stream>>>(sums, cnt, Wl0, bl0, Wl1, bl1, (float*)d_out, G, OUT);
}

// Round 3
// 808.494 us; speedup vs baseline: 1.9348x; 1.9348x over previous
//
#include <hip/hip_runtime.h>

#define FDIM 64
#define POOL_CHUNK 128   // nodes per wave in pooling

static inline size_t align_up(size_t v) { return (v + 255) & ~(size_t)255; }

// ---------------- CSR build ----------------

__global__ void k_count(const int* __restrict__ dst, int* __restrict__ deg, int E) {
    int e = blockIdx.x * blockDim.x + threadIdx.x;
    if (e < E) atomicAdd(&deg[dst[e]], 1);
}

// block sums over 1024-element chunks
__global__ void k_scan1(const int* __restrict__ deg, int* __restrict__ bsum, int n) {
    __shared__ int sh[256];
    int base = blockIdx.x * 1024;
    int t = threadIdx.x;
    int s = 0;
#pragma unroll
    for (int j = 0; j < 4; j++) {
        int i = base + t * 4 + j;
        s += (i < n) ? deg[i] : 0;
    }
    sh[t] = s;
    __syncthreads();
    for (int off = 128; off > 0; off >>= 1) {
        if (t < off) sh[t] += sh[t + off];
        __syncthreads();
    }
    if (t == 0) bsum[blockIdx.x] = sh[0];
}

// exclusive scan of block sums (nb <= 256), also write rowstart[n] = E
__global__ void k_scan2(int* __restrict__ bsum, int nb, int* __restrict__ rowstart, int n, int E) {
    if (threadIdx.x == 0) {
        int acc = 0;
        for (int i = 0; i < nb; i++) {
            int v = bsum[i];
            bsum[i] = acc;
            acc += v;
        }
        rowstart[n] = E;
    }
}

__global__ void k_scan3(const int* __restrict__ deg, const int* __restrict__ bsum,
                        int* __restrict__ rowstart, int n) {
    __shared__ int sh[256];
    int base = blockIdx.x * 1024;
    int t = threadIdx.x;
    int v[4];
    int s = 0;
#pragma unroll
    for (int j = 0; j < 4; j++) {
        int i = base + t * 4 + j;
        v[j] = (i < n) ? deg[i] : 0;
        s += v[j];
    }
    sh[t] = s;
    __syncthreads();
    // Hillis-Steele inclusive scan over 256 thread sums
    for (int off = 1; off < 256; off <<= 1) {
        int add = (t >= off) ? sh[t - off] : 0;
        __syncthreads();
        sh[t] += add;
        __syncthreads();
    }
    int excl = (t == 0 ? 0 : sh[t - 1]) + bsum[blockIdx.x];
#pragma unroll
    for (int j = 0; j < 4; j++) {
        int i = base + t * 4 + j;
        if (i < n) {
            rowstart[i] = excl;
            excl += v[j];
        }
    }
}

__global__ void k_fill(const int* __restrict__ src, const int* __restrict__ dst,
                       const int* __restrict__ rowstart, int* __restrict__ cursor,
                       int* __restrict__ adj, int E) {
    int e = blockIdx.x * blockDim.x + threadIdx.x;
    if (e < E) {
        int d = dst[e];
        int pos = rowstart[d] + atomicAdd(&cursor[d], 1);
        adj[pos] = src[e];
    }
}

// ---------------- aggregation: wave per node, lane = feature ----------------

__global__ __launch_bounds__(256) void k_agg(const float* __restrict__ h,
                                             const int* __restrict__ rowstart,
                                             const int* __restrict__ adj,
                                             float* __restrict__ agg, int n) {
    int wave = (blockIdx.x * 256 + threadIdx.x) >> 6;
    int lane = threadIdx.x & 63;
    if (wave >= n) return;
    int s0 = rowstart[wave];
    int s1 = rowstart[wave + 1];
    float acc = 0.f;
    for (int j = s0; j < s1; j++) {
        int srcn = adj[j];
        acc += h[(long)srcn * FDIM + lane];
    }
    agg[(long)wave * FDIM + lane] = acc;
}

// ---------------- fused dual GEMM + bias + optional PReLU ----------------
// Y[n,:] = prelu( A[n,:] @ Wr + X[n,:] @ Wo + b )

__global__ __launch_bounds__(256) void k_gemm(const float* __restrict__ A,
                                              const float* __restrict__ X,
                                              const float* __restrict__ Wr,
                                              const float* __restrict__ Wo,
                                              const float* __restrict__ bias,
                                              const float* __restrict__ slope_p,
                                              float* __restrict__ Y, int n, int do_prelu) {
    int node = blockIdx.x * blockDim.x + threadIdx.x;
    if (node >= n) return;
    float a[FDIM], x[FDIM];
    const float4* pa = (const float4*)(A + (long)node * FDIM);
    const float4* px = (const float4*)(X + (long)node * FDIM);
#pragma unroll
    for (int i = 0; i < FDIM / 4; i++) {
        float4 v = pa[i];
        a[4 * i] = v.x; a[4 * i + 1] = v.y; a[4 * i + 2] = v.z; a[4 * i + 3] = v.w;
    }
#pragma unroll
    for (int i = 0; i < FDIM / 4; i++) {
        float4 v = px[i];
        x[4 * i] = v.x; x[4 * i + 1] = v.y; x[4 * i + 2] = v.z; x[4 * i + 3] = v.w;
    }
    float slope = do_prelu ? slope_p[0] : 0.f;
    float4* out4 = (float4*)(Y + (long)node * FDIM);
    for (int f0 = 0; f0 < FDIM; f0 += 4) {
        float acc0 = bias[f0 + 0];
        float acc1 = bias[f0 + 1];
        float acc2 = bias[f0 + 2];
        float acc3 = bias[f0 + 3];
#pragma unroll
        for (int k = 0; k < FDIM; k++) {
            float ak = a[k];
            acc0 += ak * Wr[k * FDIM + f0 + 0];
            acc1 += ak * Wr[k * FDIM + f0 + 1];
            acc2 += ak * Wr[k * FDIM + f0 + 2];
            acc3 += ak * Wr[k * FDIM + f0 + 3];
        }
#pragma unroll
        for (int k = 0; k < FDIM; k++) {
            float xk = x[k];
            acc0 += xk * Wo[k * FDIM + f0 + 0];
            acc1 += xk * Wo[k * FDIM + f0 + 1];
            acc2 += xk * Wo[k * FDIM + f0 + 2];
            acc3 += xk * Wo[k * FDIM + f0 + 3];
        }
        if (do_prelu) {
            acc0 = acc0 >= 0.f ? acc0 : slope * acc0;
            acc1 = acc1 >= 0.f ? acc1 : slope * acc1;
            acc2 = acc2 >= 0.f ? acc2 : slope * acc2;
            acc3 = acc3 >= 0.f ? acc3 : slope * acc3;
        }
        float4 o;
        o.x = acc0; o.y = acc1; o.z = acc2; o.w = acc3;
        out4[f0 / 4] = o;
    }
}

// ---------------- global mean pool ----------------
// batch is SORTED: wave owns POOL_CHUNK contiguous nodes, lane = feature,
// register-accumulate per graph segment, flush one atomic per boundary.

__global__ __launch_bounds__(256) void k_pool(const float* __restrict__ h,
                                              const int* __restrict__ batch,
                                              float* __restrict__ sums,
                                              float* __restrict__ cnt, int n) {
    int wave = (blockIdx.x * 256 + threadIdx.x) >> 6;
    int lane = threadIdx.x & 63;
    int start = wave * POOL_CHUNK;
    if (start >= n) return;
    int end = start + POOL_CHUNK;
    if (end > n) end = n;
    int cur = batch[start];
    float acc = 0.f;
    int count = 0;
    for (int i = start; i < end; i++) {
        int g = batch[i];
        if (g != cur) {
            atomicAdd(&sums[cur * FDIM + lane], acc);
            if (lane == 0) atomicAdd(&cnt[cur], (float)count);
            acc = 0.f;
            count = 0;
            cur = g;
        }
        acc += h[(long)i * FDIM + lane];
        count++;
    }
    atomicAdd(&sums[cur * FDIM + lane], acc);
    if (lane == 0) atomicAdd(&cnt[cur], (float)count);
}

// ---------------- head: pooled @ W0 + b0, @ W1 + b1 ----------------

__global__ void k_head(const float* __restrict__ sums, const float* __restrict__ cnt,
                       const float* __restrict__ W0, const float* __restrict__ b0,
                       const float* __restrict__ W1, const float* __restrict__ b1,
                       float* __restrict__ out, int G, int OUT) {
    int g = threadIdx.x;
    if (g >= G) return;
    float c = cnt[g];
    if (c < 1.f) c = 1.f;
    float p[FDIM];
#pragma unroll
    for (int k = 0; k < FDIM; k++) p[k] = sums[g * FDIM + k] / c;
    float hid[FDIM];
    for (int f = 0; f < FDIM; f++) {
        float acc = b0[f];
#pragma unroll
        for (int k = 0; k < FDIM; k++) acc += p[k] * W0[k * FDIM + f];
        hid[f] = acc;
    }
    for (int o = 0; o < OUT; o++) {
        float acc = b1[o];
#pragma unroll
        for (int f = 0; f < FDIM; f++) acc += hid[f] * W1[f * OUT + o];
        out[g * OUT + o] = acc;
    }
}

extern "C" void kernel_launch(void* const* d_in, const int* in_sizes, int n_in,
                              void* d_out, int out_size, void* d_ws, size_t ws_size,
                              hipStream_t stream) {
    const float* x     = (const float*)d_in[0];
    const int*   ei    = (const int*)d_in[1];
    const int*   batch = (const int*)d_in[2];
    const float* W1r = (const float*)d_in[3];
    const float* b1  = (const float*)d_in[4];
    const float* W1o = (const float*)d_in[5];
    const float* W2r = (const float*)d_in[6];
    const float* b2  = (const float*)d_in[7];
    const float* W2o = (const float*)d_in[8];
    const float* W3r = (const float*)d_in[9];
    const float* b3  = (const float*)d_in[10];
    const float* W3o = (const float*)d_in[11];
    const float* a1  = (const float*)d_in[12];
    const float* a2  = (const float*)d_in[13];
    const float* Wl0 = (const float*)d_in[14];
    const float* bl0 = (const float*)d_in[15];
    const float* Wl1 = (const float*)d_in[16];
    const float* bl1 = (const float*)d_in[17];

    int N = in_sizes[0] / FDIM;
    int E = in_sizes[1] / 2;
    int OUT = in_sizes[17];
    int G = out_size / OUT;

    const int* src = ei;
    const int* dst = ei + E;

    // workspace layout
    char* w = (char*)d_ws;
    int* rowstart = (int*)w;            w += align_up((size_t)(N + 1) * 4);
    int* deg      = (int*)w;            w += align_up((size_t)N * 4);
    int* cursor   = (int*)w;            w += align_up((size_t)N * 4);
    int* bsum     = (int*)w;            w += align_up(1024 * 4);
    int* adj      = (int*)w;            w += align_up((size_t)E * 4);
    float* aggbuf = (float*)w;          w += align_up((size_t)N * FDIM * 4);
    float* h1     = (float*)w;          w += align_up((size_t)N * FDIM * 4);
    float* h2     = (float*)w;          w += align_up((size_t)N * FDIM * 4);
    float* sums   = (float*)w;          w += align_up((size_t)G * FDIM * 4);
    float* cnt    = (float*)w;          w += align_up((size_t)G * 4);

    hipMemsetAsync(deg, 0, (size_t)N * 4, stream);
    hipMemsetAsync(cursor, 0, (size_t)N * 4, stream);
    hipMemsetAsync(sums, 0, (size_t)G * FDIM * 4, stream);
    hipMemsetAsync(cnt, 0, (size_t)G * 4, stream);

    // CSR build
    k_count<<<(E + 255) / 256, 256, 0, stream>>>(dst, deg, E);
    int NB = (N + 1023) / 1024;
    k_scan1<<<NB, 256, 0, stream>>>(deg, bsum, N);
    k_scan2<<<1, 64, 0, stream>>>(bsum, NB, rowstart, N, E);
    k_scan3<<<NB, 256, 0, stream>>>(deg, bsum, rowstart, N);
    k_fill<<<(E + 255) / 256, 256, 0, stream>>>(src, dst, rowstart, cursor, adj, E);

    int aggGrid = (N + 3) / 4;       // 4 waves (nodes) per 256-thread block
    int gemmGrid = (N + 255) / 256;

    // layer 1: in = x
    k_agg<<<aggGrid, 256, 0, stream>>>(x, rowstart, adj, aggbuf, N);
    k_gemm<<<gemmGrid, 256, 0, stream>>>(aggbuf, x, W1r, W1o, b1, a1, h1, N, 1);
    // layer 2
    k_agg<<<aggGrid, 256, 0, stream>>>(h1, rowstart, adj, aggbuf, N);
    k_gemm<<<gemmGrid, 256, 0, stream>>>(aggbuf, h1, W2r, W2o, b2, a2, h2, N, 1);
    // layer 3 (no PReLU) -> reuse h1 as output
    k_agg<<<aggGrid, 256, 0, stream>>>(h2, rowstart, adj, aggbuf, N);
    k_gemm<<<gemmGrid, 256, 0, stream>>>(aggbuf, h2, W3r, W3o, b3, nullptr, h1, N, 0);

    // mean pool + head
    int poolWaves = (N + POOL_CHUNK - 1) / POOL_CHUNK;
    int poolGrid = (poolWaves + 3) / 4;   // 4 waves per 256-thread block
    k_pool<<<poolGrid, 256, 0, stream>>>(h1, batch, sums, cnt, N);
    k_head<<<1, 64, 0, stream>>>(sums, cnt, Wl0, bl0, Wl1, bl1, (float*)d_out, G, OUT);
}

// Round 4
// 478.931 us; speedup vs baseline: 3.2661x; 1.6881x over previous
//
#include <hip/hip_runtime.h>

#define FDIM 64
#define POOL_CHUNK 128   // nodes per wave in pooling

static inline size_t align_up(size_t v) { return (v + 255) & ~(size_t)255; }

__device__ __forceinline__ float bcastf(float v, int l) {
    return __int_as_float(__builtin_amdgcn_readlane(__float_as_int(v), l));
}

// ---------------- CSR build ----------------

__global__ void k_count(const int* __restrict__ dst, int* __restrict__ deg, int E) {
    int e = blockIdx.x * blockDim.x + threadIdx.x;
    if (e < E) atomicAdd(&deg[dst[e]], 1);
}

// block sums over 1024-element chunks
__global__ void k_scan1(const int* __restrict__ deg, int* __restrict__ bsum, int n) {
    __shared__ int sh[256];
    int base = blockIdx.x * 1024;
    int t = threadIdx.x;
    int s = 0;
#pragma unroll
    for (int j = 0; j < 4; j++) {
        int i = base + t * 4 + j;
        s += (i < n) ? deg[i] : 0;
    }
    sh[t] = s;
    __syncthreads();
    for (int off = 128; off > 0; off >>= 1) {
        if (t < off) sh[t] += sh[t + off];
        __syncthreads();
    }
    if (t == 0) bsum[blockIdx.x] = sh[0];
}

// exclusive scan of block sums (nb <= 256), also write rowstart[n] = E
__global__ void k_scan2(int* __restrict__ bsum, int nb, int* __restrict__ rowstart, int n, int E) {
    if (threadIdx.x == 0) {
        int acc = 0;
        for (int i = 0; i < nb; i++) {
            int v = bsum[i];
            bsum[i] = acc;
            acc += v;
        }
        rowstart[n] = E;
    }
}

__global__ void k_scan3(const int* __restrict__ deg, const int* __restrict__ bsum,
                        int* __restrict__ rowstart, int n) {
    __shared__ int sh[256];
    int base = blockIdx.x * 1024;
    int t = threadIdx.x;
    int v[4];
    int s = 0;
#pragma unroll
    for (int j = 0; j < 4; j++) {
        int i = base + t * 4 + j;
        v[j] = (i < n) ? deg[i] : 0;
        s += v[j];
    }
    sh[t] = s;
    __syncthreads();
    // Hillis-Steele inclusive scan over 256 thread sums
    for (int off = 1; off < 256; off <<= 1) {
        int add = (t >= off) ? sh[t - off] : 0;
        __syncthreads();
        sh[t] += add;
        __syncthreads();
    }
    int excl = (t == 0 ? 0 : sh[t - 1]) + bsum[blockIdx.x];
#pragma unroll
    for (int j = 0; j < 4; j++) {
        int i = base + t * 4 + j;
        if (i < n) {
            rowstart[i] = excl;
            excl += v[j];
        }
    }
}

__global__ void k_fill(const int* __restrict__ src, const int* __restrict__ dst,
                       const int* __restrict__ rowstart, int* __restrict__ cursor,
                       int* __restrict__ adj, int E) {
    int e = blockIdx.x * blockDim.x + threadIdx.x;
    if (e < E) {
        int d = dst[e];
        int pos = rowstart[d] + atomicAdd(&cursor[d], 1);
        adj[pos] = src[e];
    }
}

// ---------------- fused layer: agg + dual GEMV + bias + PReLU ----------------
// wave per node, lane = feature. Weight columns live in VGPRs (reused across
// the wave's node strip); a[k]/x[k] broadcast via v_readlane.

__global__ __launch_bounds__(256, 2) void k_layer(
    const float* __restrict__ Hin, const int* __restrict__ rowstart,
    const int* __restrict__ adj, const float* __restrict__ Wr,
    const float* __restrict__ Wo, const float* __restrict__ bias,
    const float* __restrict__ slope_p, float* __restrict__ Hout,
    int n, int do_prelu)
{
    int lane = threadIdx.x & 63;
    int wid  = (blockIdx.x * blockDim.x + threadIdx.x) >> 6;
    int nw   = (gridDim.x * blockDim.x) >> 6;

    // per-lane weight columns: wr[k] = Wr[k][lane]
    float wr[FDIM], wo[FDIM];
#pragma unroll
    for (int k = 0; k < FDIM; k++) wr[k] = Wr[k * FDIM + lane];
#pragma unroll
    for (int k = 0; k < FDIM; k++) wo[k] = Wo[k * FDIM + lane];
    float bv = bias[lane];
    float slope = do_prelu ? slope_p[0] : 1.0f;   // slope=1 => identity

    for (int node = wid; node < n; node += nw) {
        int s0 = rowstart[node], s1 = rowstart[node + 1];
        float agg = 0.f;
        for (int j = s0; j < s1; j += 64) {
            int idx = adj[j + lane];              // coalesced (adj padded by 64)
            int lim = s1 - j; if (lim > 64) lim = 64;
            int t = 0;
            for (; t + 4 <= lim; t += 4) {
                int i0 = __shfl(idx, t + 0, 64);
                int i1 = __shfl(idx, t + 1, 64);
                int i2 = __shfl(idx, t + 2, 64);
                int i3 = __shfl(idx, t + 3, 64);
                float v0 = Hin[(long)i0 * FDIM + lane];
                float v1 = Hin[(long)i1 * FDIM + lane];
                float v2 = Hin[(long)i2 * FDIM + lane];
                float v3 = Hin[(long)i3 * FDIM + lane];
                agg += (v0 + v1) + (v2 + v3);
            }
            for (; t < lim; t++) {
                int i0 = __shfl(idx, t, 64);
                agg += Hin[(long)i0 * FDIM + lane];
            }
        }
        float xv = Hin[(long)node * FDIM + lane];

        float pa0 = 0.f, pa1 = 0.f, pa2 = 0.f, pa3 = 0.f;
        float px0 = 0.f, px1 = 0.f, px2 = 0.f, px3 = 0.f;
#pragma unroll
        for (int k = 0; k < FDIM; k += 4) {
            pa0 += bcastf(agg, k + 0) * wr[k + 0];
            px0 += bcastf(xv,  k + 0) * wo[k + 0];
            pa1 += bcastf(agg, k + 1) * wr[k + 1];
            px1 += bcastf(xv,  k + 1) * wo[k + 1];
            pa2 += bcastf(agg, k + 2) * wr[k + 2];
            px2 += bcastf(xv,  k + 2) * wo[k + 2];
            pa3 += bcastf(agg, k + 3) * wr[k + 3];
            px3 += bcastf(xv,  k + 3) * wo[k + 3];
        }
        float acc = bv + ((pa0 + pa1) + (pa2 + pa3)) + ((px0 + px1) + (px2 + px3));
        acc = acc >= 0.f ? acc : slope * acc;
        Hout[(long)node * FDIM + lane] = acc;     // coalesced 256B store
    }
}

// ---------------- global mean pool ----------------
// batch SORTED: wave owns POOL_CHUNK contiguous nodes, lane = feature,
// register-accumulate per graph segment, flush one atomic per boundary.

__global__ __launch_bounds__(256) void k_pool(const float* __restrict__ h,
                                              const int* __restrict__ batch,
                                              float* __restrict__ sums,
                                              float* __restrict__ cnt, int n) {
    int wave = (blockIdx.x * 256 + threadIdx.x) >> 6;
    int lane = threadIdx.x & 63;
    int start = wave * POOL_CHUNK;
    if (start >= n) return;
    int end = start + POOL_CHUNK;
    if (end > n) end = n;
    int cur = batch[start];
    float acc = 0.f;
    int count = 0;
    for (int i = start; i < end; i++) {
        int g = batch[i];
        if (g != cur) {
            atomicAdd(&sums[cur * FDIM + lane], acc);
            if (lane == 0) atomicAdd(&cnt[cur], (float)count);
            acc = 0.f;
            count = 0;
            cur = g;
        }
        acc += h[(long)i * FDIM + lane];
        count++;
    }
    atomicAdd(&sums[cur * FDIM + lane], acc);
    if (lane == 0) atomicAdd(&cnt[cur], (float)count);
}

// ---------------- head: one wave per graph ----------------

__global__ __launch_bounds__(64) void k_head(const float* __restrict__ sums,
                                             const float* __restrict__ cnt,
                                             const float* __restrict__ W0,
                                             const float* __restrict__ b0,
                                             const float* __restrict__ W1,
                                             const float* __restrict__ b1,
                                             float* __restrict__ out, int OUT) {
    int g = blockIdx.x;
    int lane = threadIdx.x;
    float c = cnt[g];
    if (c < 1.f) c = 1.f;
    float p = sums[g * FDIM + lane] / c;

    float h0 = 0.f, h1 = 0.f, h2 = 0.f, h3 = 0.f;
#pragma unroll
    for (int k = 0; k < FDIM; k += 4) {
        h0 += bcastf(p, k + 0) * W0[(k + 0) * FDIM + lane];
        h1 += bcastf(p, k + 1) * W0[(k + 1) * FDIM + lane];
        h2 += bcastf(p, k + 2) * W0[(k + 2) * FDIM + lane];
        h3 += bcastf(p, k + 3) * W0[(k + 3) * FDIM + lane];
    }
    float hid = b0[lane] + ((h0 + h1) + (h2 + h3));
    for (int o = 0; o < OUT; o++) {
        float part = hid * W1[lane * OUT + o];
#pragma unroll
        for (int m = 32; m >= 1; m >>= 1) part += __shfl_xor(part, m, 64);
        if (lane == 0) out[g * OUT + o] = part + b1[o];
    }
}

extern "C" void kernel_launch(void* const* d_in, const int* in_sizes, int n_in,
                              void* d_out, int out_size, void* d_ws, size_t ws_size,
                              hipStream_t stream) {
    const float* x     = (const float*)d_in[0];
    const int*   ei    = (const int*)d_in[1];
    const int*   batch = (const int*)d_in[2];
    const float* W1r = (const float*)d_in[3];
    const float* b1  = (const float*)d_in[4];
    const float* W1o = (const float*)d_in[5];
    const float* W2r = (const float*)d_in[6];
    const float* b2  = (const float*)d_in[7];
    const float* W2o = (const float*)d_in[8];
    const float* W3r = (const float*)d_in[9];
    const float* b3  = (const float*)d_in[10];
    const float* W3o = (const float*)d_in[11];
    const float* a1  = (const float*)d_in[12];
    const float* a2  = (const float*)d_in[13];
    const float* Wl0 = (const float*)d_in[14];
    const float* bl0 = (const float*)d_in[15];
    const float* Wl1 = (const float*)d_in[16];
    const float* bl1 = (const float*)d_in[17];

    int N = in_sizes[0] / FDIM;
    int E = in_sizes[1] / 2;
    int OUT = in_sizes[17];
    int G = out_size / OUT;

    const int* src = ei;
    const int* dst = ei + E;

    // workspace layout
    char* w = (char*)d_ws;
    int* rowstart = (int*)w;            w += align_up((size_t)(N + 1) * 4);
    int* deg      = (int*)w;            w += align_up((size_t)N * 4);
    int* cursor   = (int*)w;            w += align_up((size_t)N * 4);
    int* bsum     = (int*)w;            w += align_up(1024 * 4);
    int* adj      = (int*)w;            w += align_up((size_t)E * 4 + 256);  // +64-int pad for coalesced tail read
    float* h1     = (float*)w;          w += align_up((size_t)N * FDIM * 4);
    float* h2     = (float*)w;          w += align_up((size_t)N * FDIM * 4);
    float* sums   = (float*)w;          w += align_up((size_t)G * FDIM * 4);
    float* cnt    = (float*)w;          w += align_up((size_t)G * 4);

    hipMemsetAsync(deg, 0, (size_t)N * 4, stream);
    hipMemsetAsync(cursor, 0, (size_t)N * 4, stream);
    hipMemsetAsync(sums, 0, (size_t)G * FDIM * 4, stream);
    hipMemsetAsync(cnt, 0, (size_t)G * 4, stream);

    // CSR build
    k_count<<<(E + 255) / 256, 256, 0, stream>>>(dst, deg, E);
    int NB = (N + 1023) / 1024;
    k_scan1<<<NB, 256, 0, stream>>>(deg, bsum, N);
    k_scan2<<<1, 64, 0, stream>>>(bsum, NB, rowstart, N, E);
    k_scan3<<<NB, 256, 0, stream>>>(deg, bsum, rowstart, N);
    k_fill<<<(E + 255) / 256, 256, 0, stream>>>(src, dst, rowstart, cursor, adj, E);

    // fused layers (wave per node; 768 blocks * 4 waves = 3072 waves)
    int layerGrid = 768;
    k_layer<<<layerGrid, 256, 0, stream>>>(x,  rowstart, adj, W1r, W1o, b1, a1, h1, N, 1);
    k_layer<<<layerGrid, 256, 0, stream>>>(h1, rowstart, adj, W2r, W2o, b2, a2, h2, N, 1);
    k_layer<<<layerGrid, 256, 0, stream>>>(h2, rowstart, adj, W3r, W3o, b3, nullptr, h1, N, 0);

    // mean pool + head
    int poolWaves = (N + POOL_CHUNK - 1) / POOL_CHUNK;
    int poolGrid = (poolWaves + 3) / 4;
    k_pool<<<poolGrid, 256, 0, stream>>>(h1, batch, sums, cnt, N);
    k_head<<<G, 64, 0, stream>>>(sums, cnt, Wl0, bl0, Wl1, bl1, (float*)d_out, OUT);
}

// Round 8
// 456.554 us; speedup vs baseline: 3.4262x; 1.0490x over previous
//
#include <hip/hip_runtime.h>

#define FDIM 64
#define POOL_CHUNK 64    // nodes per wave in pooling

static inline size_t align_up(size_t v) { return (v + 255) & ~(size_t)255; }

__device__ __forceinline__ float bcastf(float v, int l) {
    return __int_as_float(__builtin_amdgcn_readlane(__float_as_int(v), l));
}

// ---------------- CSR build ----------------

__global__ void k_count(const int* __restrict__ dst, int* __restrict__ deg, int E) {
    int e = blockIdx.x * blockDim.x + threadIdx.x;
    if (e < E) atomicAdd(&deg[dst[e]], 1);
}

// block sums over 1024-element chunks
__global__ void k_scan1(const int* __restrict__ deg, int* __restrict__ bsum, int n) {
    __shared__ int sh[256];
    int base = blockIdx.x * 1024;
    int t = threadIdx.x;
    int s = 0;
#pragma unroll
    for (int j = 0; j < 4; j++) {
        int i = base + t * 4 + j;
        s += (i < n) ? deg[i] : 0;
    }
    sh[t] = s;
    __syncthreads();
    for (int off = 128; off > 0; off >>= 1) {
        if (t < off) sh[t] += sh[t + off];
        __syncthreads();
    }
    if (t == 0) bsum[blockIdx.x] = sh[0];
}

// exclusive scan of block sums (nb <= 256), also write rowstart[n] = E
__global__ void k_scan2(int* __restrict__ bsum, int nb, int* __restrict__ rowstart, int n, int E) {
    if (threadIdx.x == 0) {
        int acc = 0;
        for (int i = 0; i < nb; i++) {
            int v = bsum[i];
            bsum[i] = acc;
            acc += v;
        }
        rowstart[n] = E;
    }
}

__global__ void k_scan3(const int* __restrict__ deg, const int* __restrict__ bsum,
                        int* __restrict__ rowstart, int n) {
    __shared__ int sh[256];
    int base = blockIdx.x * 1024;
    int t = threadIdx.x;
    int v[4];
    int s = 0;
#pragma unroll
    for (int j = 0; j < 4; j++) {
        int i = base + t * 4 + j;
        v[j] = (i < n) ? deg[i] : 0;
        s += v[j];
    }
    sh[t] = s;
    __syncthreads();
    // Hillis-Steele inclusive scan over 256 thread sums
    for (int off = 1; off < 256; off <<= 1) {
        int add = (t >= off) ? sh[t - off] : 0;
        __syncthreads();
        sh[t] += add;
        __syncthreads();
    }
    int excl = (t == 0 ? 0 : sh[t - 1]) + bsum[blockIdx.x];
#pragma unroll
    for (int j = 0; j < 4; j++) {
        int i = base + t * 4 + j;
        if (i < n) {
            rowstart[i] = excl;
            excl += v[j];
        }
    }
}

__global__ void k_fill(const int* __restrict__ src, const int* __restrict__ dst,
                       const int* __restrict__ rowstart, int* __restrict__ cursor,
                       int* __restrict__ adj, int E) {
    int e = blockIdx.x * blockDim.x + threadIdx.x;
    if (e < E) {
        int d = dst[e];
        int pos = rowstart[d] + atomicAdd(&cursor[d], 1);
        adj[pos] = src[e];
    }
}

// ---------------- fused layer: agg + dual GEMV + bias + PReLU ----------------
// wave per node, lane = feature. 8 independent gather loads in flight per
// round; weight columns per lane; a[k]/x[k] broadcast via v_readlane.

__global__ __launch_bounds__(256, 2) void k_layer(
    const float* __restrict__ Hin, const int* __restrict__ rowstart,
    const int* __restrict__ adj, const float* __restrict__ Wr,
    const float* __restrict__ Wo, const float* __restrict__ bias,
    const float* __restrict__ slope_p, float* __restrict__ Hout,
    int n, int do_prelu)
{
    int lane = threadIdx.x & 63;
    int wid  = (blockIdx.x * blockDim.x + threadIdx.x) >> 6;
    int nw   = (gridDim.x * blockDim.x) >> 6;

    // per-lane weight columns: wr[k] = Wr[k][lane]
    float wr[FDIM], wo[FDIM];
#pragma unroll
    for (int k = 0; k < FDIM; k++) wr[k] = Wr[k * FDIM + lane];
#pragma unroll
    for (int k = 0; k < FDIM; k++) wo[k] = Wo[k * FDIM + lane];
    float bv = bias[lane];
    float slope = do_prelu ? slope_p[0] : 1.0f;   // slope=1 => identity

    for (int node = wid; node < n; node += nw) {
        int s0 = rowstart[node], s1 = rowstart[node + 1];
        float agg = 0.f;
        for (int j = s0; j < s1; j += 64) {
            int idx = adj[j + lane];              // coalesced (adj padded by 64)
            int lim = s1 - j; if (lim > 64) lim = 64;
            int t = 0;
            for (; t + 8 <= lim; t += 8) {
                int i0 = __shfl(idx, t + 0, 64);
                int i1 = __shfl(idx, t + 1, 64);
                int i2 = __shfl(idx, t + 2, 64);
                int i3 = __shfl(idx, t + 3, 64);
                int i4 = __shfl(idx, t + 4, 64);
                int i5 = __shfl(idx, t + 5, 64);
                int i6 = __shfl(idx, t + 6, 64);
                int i7 = __shfl(idx, t + 7, 64);
                float v0 = Hin[(long)i0 * FDIM + lane];
                float v1 = Hin[(long)i1 * FDIM + lane];
                float v2 = Hin[(long)i2 * FDIM + lane];
                float v3 = Hin[(long)i3 * FDIM + lane];
                float v4 = Hin[(long)i4 * FDIM + lane];
                float v5 = Hin[(long)i5 * FDIM + lane];
                float v6 = Hin[(long)i6 * FDIM + lane];
                float v7 = Hin[(long)i7 * FDIM + lane];
                agg += ((v0 + v1) + (v2 + v3)) + ((v4 + v5) + (v6 + v7));
            }
            for (; t + 4 <= lim; t += 4) {
                int i0 = __shfl(idx, t + 0, 64);
                int i1 = __shfl(idx, t + 1, 64);
                int i2 = __shfl(idx, t + 2, 64);
                int i3 = __shfl(idx, t + 3, 64);
                float v0 = Hin[(long)i0 * FDIM + lane];
                float v1 = Hin[(long)i1 * FDIM + lane];
                float v2 = Hin[(long)i2 * FDIM + lane];
                float v3 = Hin[(long)i3 * FDIM + lane];
                agg += (v0 + v1) + (v2 + v3);
            }
            for (; t < lim; t++) {
                int i0 = __shfl(idx, t, 64);
                agg += Hin[(long)i0 * FDIM + lane];
            }
        }
        float xv = Hin[(long)node * FDIM + lane];

        float pa0 = 0.f, pa1 = 0.f, pa2 = 0.f, pa3 = 0.f;
        float px0 = 0.f, px1 = 0.f, px2 = 0.f, px3 = 0.f;
#pragma unroll
        for (int k = 0; k < FDIM; k += 4) {
            pa0 += bcastf(agg, k + 0) * wr[k + 0];
            px0 += bcastf(xv,  k + 0) * wo[k + 0];
            pa1 += bcastf(agg, k + 1) * wr[k + 1];
            px1 += bcastf(xv,  k + 1) * wo[k + 1];
            pa2 += bcastf(agg, k + 2) * wr[k + 2];
            px2 += bcastf(xv,  k + 2) * wo[k + 2];
            pa3 += bcastf(agg, k + 3) * wr[k + 3];
            px3 += bcastf(xv,  k + 3) * wo[k + 3];
        }
        float acc = bv + ((pa0 + pa1) + (pa2 + pa3)) + ((px0 + px1) + (px2 + px3));
        acc = acc >= 0.f ? acc : slope * acc;
        Hout[(long)node * FDIM + lane] = acc;     // coalesced 256B store
    }
}

// ---------------- global mean pool ----------------
// batch SORTED: wave owns POOL_CHUNK contiguous nodes, lane = feature,
// register-accumulate per graph segment, flush one atomic per boundary.

__global__ __launch_bounds__(256) void k_pool(const float* __restrict__ h,
                                              const int* __restrict__ batch,
                                              float* __restrict__ sums,
                                              float* __restrict__ cnt, int n) {
    int wave = (blockIdx.x * 256 + threadIdx.x) >> 6;
    int lane = threadIdx.x & 63;
    int start = wave * POOL_CHUNK;
    if (start >= n) return;
    int end = start + POOL_CHUNK;
    if (end > n) end = n;
    int cur = batch[start];
    float acc = 0.f;
    int count = 0;
#pragma unroll 4
    for (int i = start; i < end; i++) {
        int g = batch[i];
        if (g != cur) {
            atomicAdd(&sums[cur * FDIM + lane], acc);
            if (lane == 0) atomicAdd(&cnt[cur], (float)count);
            acc = 0.f;
            count = 0;
            cur = g;
        }
        acc += h[(long)i * FDIM + lane];
        count++;
    }
    atomicAdd(&sums[cur * FDIM + lane], acc);
    if (lane == 0) atomicAdd(&cnt[cur], (float)count);
}

// ---------------- head: one wave per graph ----------------

__global__ __launch_bounds__(64) void k_head(const float* __restrict__ sums,
                                             const float* __restrict__ cnt,
                                             const float* __restrict__ W0,
                                             const float* __restrict__ b0,
                                             const float* __restrict__ W1,
                                             const float* __restrict__ b1,
                                             float* __restrict__ out, int OUT) {
    int g = blockIdx.x;
    int lane = threadIdx.x;
    float c = cnt[g];
    if (c < 1.f) c = 1.f;
    float p = sums[g * FDIM + lane] / c;

    float h0 = 0.f, h1 = 0.f, h2 = 0.f, h3 = 0.f;
#pragma unroll
    for (int k = 0; k < FDIM; k += 4) {
        h0 += bcastf(p, k + 0) * W0[(k + 0) * FDIM + lane];
        h1 += bcastf(p, k + 1) * W0[(k + 1) * FDIM + lane];
        h2 += bcastf(p, k + 2) * W0[(k + 2) * FDIM + lane];
        h3 += bcastf(p, k + 3) * W0[(k + 3) * FDIM + lane];
    }
    float hid = b0[lane] + ((h0 + h1) + (h2 + h3));
    for (int o = 0; o < OUT; o++) {
        float part = hid * W1[lane * OUT + o];
#pragma unroll
        for (int m = 32; m >= 1; m >>= 1) part += __shfl_xor(part, m, 64);
        if (lane == 0) out[g * OUT + o] = part + b1[o];
    }
}

extern "C" void kernel_launch(void* const* d_in, const int* in_sizes, int n_in,
                              void* d_out, int out_size, void* d_ws, size_t ws_size,
                              hipStream_t stream) {
    const float* x     = (const float*)d_in[0];
    const int*   ei    = (const int*)d_in[1];
    const int*   batch = (const int*)d_in[2];
    const float* W1r = (const float*)d_in[3];
    const float* b1  = (const float*)d_in[4];
    const float* W1o = (const float*)d_in[5];
    const float* W2r = (const float*)d_in[6];
    const float* b2  = (const float*)d_in[7];
    const float* W2o = (const float*)d_in[8];
    const float* W3r = (const float*)d_in[9];
    const float* b3  = (const float*)d_in[10];
    const float* W3o = (const float*)d_in[11];
    const float* a1  = (const float*)d_in[12];
    const float* a2  = (const float*)d_in[13];
    const float* Wl0 = (const float*)d_in[14];
    const float* bl0 = (const float*)d_in[15];
    const float* Wl1 = (const float*)d_in[16];
    const float* bl1 = (const float*)d_in[17];

    int N = in_sizes[0] / FDIM;
    int E = in_sizes[1] / 2;
    int OUT = in_sizes[17];
    int G = out_size / OUT;

    const int* src = ei;
    const int* dst = ei + E;

    // workspace layout
    char* w = (char*)d_ws;
    int* rowstart = (int*)w;            w += align_up((size_t)(N + 1) * 4);
    int* deg      = (int*)w;            w += align_up((size_t)N * 4);
    int* cursor   = (int*)w;            w += align_up((size_t)N * 4);
    int* bsum     = (int*)w;            w += align_up(1024 * 4);
    int* adj      = (int*)w;            w += align_up((size_t)E * 4 + 256);  // +64-int pad for coalesced tail read
    float* h1     = (float*)w;          w += align_up((size_t)N * FDIM * 4);
    float* h2     = (float*)w;          w += align_up((size_t)N * FDIM * 4);
    float* sums   = (float*)w;          w += align_up((size_t)G * FDIM * 4);
    float* cnt    = (float*)w;          w += align_up((size_t)G * 4);

    hipMemsetAsync(deg, 0, (size_t)N * 4, stream);
    hipMemsetAsync(cursor, 0, (size_t)N * 4, stream);
    hipMemsetAsync(sums, 0, (size_t)G * FDIM * 4, stream);
    hipMemsetAsync(cnt, 0, (size_t)G * 4, stream);

    // CSR build
    k_count<<<(E + 255) / 256, 256, 0, stream>>>(dst, deg, E);
    int NB = (N + 1023) / 1024;
    k_scan1<<<NB, 256, 0, stream>>>(deg, bsum, N);
    k_scan2<<<1, 64, 0, stream>>>(bsum, NB, rowstart, N, E);
    k_scan3<<<NB, 256, 0, stream>>>(deg, bsum, rowstart, N);
    k_fill<<<(E + 255) / 256, 256, 0, stream>>>(src, dst, rowstart, cursor, adj, E);

    // fused layers (wave per node; 2048 blocks * 4 waves = 8192 waves, 8/SIMD)
    int layerGrid = 2048;
    k_layer<<<layerGrid, 256, 0, stream>>>(x,  rowstart, adj, W1r, W1o, b1, a1, h1, N, 1);
    k_layer<<<layerGrid, 256, 0, stream>>>(h1, rowstart, adj, W2r, W2o, b2, a2, h2, N, 1);
    k_layer<<<layerGrid, 256, 0, stream>>>(h2, rowstart, adj, W3r, W3o, b3, nullptr, h1, N, 0);

    // mean pool + head
    int poolWaves = (N + POOL_CHUNK - 1) / POOL_CHUNK;
    int poolGrid = (poolWaves + 3) / 4;
    k_pool<<<poolGrid, 256, 0, stream>>>(h1, batch, sums, cnt, N);
    k_head<<<G, 64, 0, stream>>>(sums, cnt, Wl0, bl0, Wl1, bl1, (float*)d_out, OUT);
}

// Round 9
// 453.494 us; speedup vs baseline: 3.4493x; 1.0067x over previous
//
#include <hip/hip_runtime.h>

#define FDIM 64
#define POOL_CHUNK 64    // nodes per wave in pooling

typedef unsigned int uint32;

static inline size_t align_up(size_t v) { return (v + 255) & ~(size_t)255; }

__device__ __forceinline__ float bcastf(float v, int l) {
    return __int_as_float(__builtin_amdgcn_readlane(__float_as_int(v), l));
}
__device__ __forceinline__ float bf_lo(uint32 u) { return __uint_as_float(u << 16); }
__device__ __forceinline__ float bf_hi(uint32 u) { return __uint_as_float(u & 0xFFFF0000u); }
__device__ __forceinline__ unsigned short f2bf(float f) {   // RNE
    uint32 u = __float_as_uint(f);
    return (unsigned short)((u + 0x7FFFu + ((u >> 16) & 1u)) >> 16);
}
__device__ __forceinline__ float bf2f(unsigned short s) {
    return __uint_as_float(((uint32)s) << 16);
}

// ---------------- CSR build ----------------

__global__ void k_count(const int* __restrict__ dst, int* __restrict__ deg, int E) {
    int e = blockIdx.x * blockDim.x + threadIdx.x;
    if (e < E) atomicAdd(&deg[dst[e]], 1);
}

__global__ void k_scan1(const int* __restrict__ deg, int* __restrict__ bsum, int n) {
    __shared__ int sh[256];
    int base = blockIdx.x * 1024;
    int t = threadIdx.x;
    int s = 0;
#pragma unroll
    for (int j = 0; j < 4; j++) {
        int i = base + t * 4 + j;
        s += (i < n) ? deg[i] : 0;
    }
    sh[t] = s;
    __syncthreads();
    for (int off = 128; off > 0; off >>= 1) {
        if (t < off) sh[t] += sh[t + off];
        __syncthreads();
    }
    if (t == 0) bsum[blockIdx.x] = sh[0];
}

__global__ void k_scan2(int* __restrict__ bsum, int nb, int* __restrict__ rowstart, int n, int E) {
    if (threadIdx.x == 0) {
        int acc = 0;
        for (int i = 0; i < nb; i++) {
            int v = bsum[i];
            bsum[i] = acc;
            acc += v;
        }
        rowstart[n] = E;
    }
}

__global__ void k_scan3(const int* __restrict__ deg, const int* __restrict__ bsum,
                        int* __restrict__ rowstart, int n) {
    __shared__ int sh[256];
    int base = blockIdx.x * 1024;
    int t = threadIdx.x;
    int v[4];
    int s = 0;
#pragma unroll
    for (int j = 0; j < 4; j++) {
        int i = base + t * 4 + j;
        v[j] = (i < n) ? deg[i] : 0;
        s += v[j];
    }
    sh[t] = s;
    __syncthreads();
    for (int off = 1; off < 256; off <<= 1) {
        int add = (t >= off) ? sh[t - off] : 0;
        __syncthreads();
        sh[t] += add;
        __syncthreads();
    }
    int excl = (t == 0 ? 0 : sh[t - 1]) + bsum[blockIdx.x];
#pragma unroll
    for (int j = 0; j < 4; j++) {
        int i = base + t * 4 + j;
        if (i < n) {
            rowstart[i] = excl;
            excl += v[j];
        }
    }
}

__global__ void k_fill(const int* __restrict__ src, const int* __restrict__ dst,
                       const int* __restrict__ rowstart, int* __restrict__ cursor,
                       int* __restrict__ adj, int E) {
    int e = blockIdx.x * blockDim.x + threadIdx.x;
    if (e < E) {
        int d = dst[e];
        int pos = rowstart[d] + atomicAdd(&cursor[d], 1);
        adj[pos] = src[e];
    }
}

// ---------------- fp32 -> bf16 row conversion ----------------

__global__ void k_cvt(const float* __restrict__ in, unsigned short* __restrict__ out, long n4) {
    long i = (long)blockIdx.x * blockDim.x + threadIdx.x;
    long stride = (long)gridDim.x * blockDim.x;
    for (; i < n4; i += stride) {
        float4 v = ((const float4*)in)[i];
        uint2 o;
        o.x = (uint32)f2bf(v.x) | ((uint32)f2bf(v.y) << 16);
        o.y = (uint32)f2bf(v.z) | ((uint32)f2bf(v.w) << 16);
        ((uint2*)out)[i] = o;
    }
}

// ---------------- fused layer: bf16 agg + dual GEMV + bias + PReLU --------
// wave per node. Gather: bf16 rows (128B); 32 lanes x 2 features cover one
// row, the two half-waves process 2 edges per load. fp32 accumulate.
// Weight columns (fp32) per lane; broadcasts via v_readlane.

__global__ __launch_bounds__(256, 2) void k_layer(
    const unsigned short* __restrict__ Hbf, const int* __restrict__ rowstart,
    const int* __restrict__ adj, const float* __restrict__ Wr,
    const float* __restrict__ Wo, const float* __restrict__ bias,
    const float* __restrict__ slope_p, unsigned short* __restrict__ HbfOut,
    int n, int do_prelu)
{
    int lane  = threadIdx.x & 63;
    int half  = lane >> 5;
    int fpair = (lane & 31) * 2;
    int wid   = (blockIdx.x * blockDim.x + threadIdx.x) >> 6;
    int nw    = (gridDim.x * blockDim.x) >> 6;

    float wr[FDIM], wo[FDIM];
#pragma unroll
    for (int k = 0; k < FDIM; k++) wr[k] = Wr[k * FDIM + lane];
#pragma unroll
    for (int k = 0; k < FDIM; k++) wo[k] = Wo[k * FDIM + lane];
    float bv = bias[lane];
    float slope = do_prelu ? slope_p[0] : 1.0f;   // slope=1 => identity

    for (int node = wid; node < n; node += nw) {
        int s0 = rowstart[node], s1 = rowstart[node + 1];
        float agg0 = 0.f, agg1 = 0.f;
        for (int j = s0; j < s1; j += 64) {
            int idx = adj[j + lane];              // coalesced (adj padded)
            int lim = s1 - j; if (lim > 64) lim = 64;
            int t = 0;
            for (; t + 8 <= lim; t += 8) {        // 4 pairs: 4 loads in flight
                int ia0 = __shfl(idx, t + 0, 64), ib0 = __shfl(idx, t + 1, 64);
                int ia1 = __shfl(idx, t + 2, 64), ib1 = __shfl(idx, t + 3, 64);
                int ia2 = __shfl(idx, t + 4, 64), ib2 = __shfl(idx, t + 5, 64);
                int ia3 = __shfl(idx, t + 6, 64), ib3 = __shfl(idx, t + 7, 64);
                long r0 = half ? ib0 : ia0;
                long r1 = half ? ib1 : ia1;
                long r2 = half ? ib2 : ia2;
                long r3 = half ? ib3 : ia3;
                uint32 u0 = *(const uint32*)(Hbf + (r0 << 6) + fpair);
                uint32 u1 = *(const uint32*)(Hbf + (r1 << 6) + fpair);
                uint32 u2 = *(const uint32*)(Hbf + (r2 << 6) + fpair);
                uint32 u3 = *(const uint32*)(Hbf + (r3 << 6) + fpair);
                agg0 += (bf_lo(u0) + bf_lo(u1)) + (bf_lo(u2) + bf_lo(u3));
                agg1 += (bf_hi(u0) + bf_hi(u1)) + (bf_hi(u2) + bf_hi(u3));
            }
            for (; t + 2 <= lim; t += 2) {
                int ia = __shfl(idx, t, 64), ib = __shfl(idx, t + 1, 64);
                long r = half ? ib : ia;
                uint32 u = *(const uint32*)(Hbf + (r << 6) + fpair);
                agg0 += bf_lo(u);
                agg1 += bf_hi(u);
            }
            if (t < lim) {                        // odd leftover: half 0 only
                int ia = __shfl(idx, t, 64);
                if (half == 0) {
                    uint32 u = *(const uint32*)(Hbf + ((long)ia << 6) + fpair);
                    agg0 += bf_lo(u);
                    agg1 += bf_hi(u);
                }
            }
        }
        // combine the two half-wave partial sums (both halves get the total)
        agg0 += __shfl_xor(agg0, 32, 64);
        agg1 += __shfl_xor(agg1, 32, 64);

        float xv = bf2f(Hbf[((long)node << 6) + lane]);   // self row, feature=lane

        float pa0 = 0.f, pa1 = 0.f, pa2 = 0.f, pa3 = 0.f;
        float px0 = 0.f, px1 = 0.f, px2 = 0.f, px3 = 0.f;
#pragma unroll
        for (int k = 0; k < FDIM; k += 4) {
            int l2 = k >> 1;
            // feature k (even) lives in agg0 of lane k/2; k+1 in agg1 of lane k/2
            pa0 += bcastf(agg0, l2 + 0) * wr[k + 0];
            pa1 += bcastf(agg1, l2 + 0) * wr[k + 1];
            pa2 += bcastf(agg0, l2 + 1) * wr[k + 2];
            pa3 += bcastf(agg1, l2 + 1) * wr[k + 3];
            px0 += bcastf(xv, k + 0) * wo[k + 0];
            px1 += bcastf(xv, k + 1) * wo[k + 1];
            px2 += bcastf(xv, k + 2) * wo[k + 2];
            px3 += bcastf(xv, k + 3) * wo[k + 3];
        }
        float acc = bv + ((pa0 + pa1) + (pa2 + pa3)) + ((px0 + px1) + (px2 + px3));
        acc = acc >= 0.f ? acc : slope * acc;
        HbfOut[((long)node << 6) + lane] = f2bf(acc);     // coalesced 128B store
    }
}

// ---------------- global mean pool (bf16 input) ----------------

__global__ __launch_bounds__(256) void k_pool(const unsigned short* __restrict__ h,
                                              const int* __restrict__ batch,
                                              float* __restrict__ sums,
                                              float* __restrict__ cnt, int n) {
    int wave = (blockIdx.x * 256 + threadIdx.x) >> 6;
    int lane = threadIdx.x & 63;
    int start = wave * POOL_CHUNK;
    if (start >= n) return;
    int end = start + POOL_CHUNK;
    if (end > n) end = n;
    int cur = batch[start];
    float acc = 0.f;
    int count = 0;
#pragma unroll 4
    for (int i = start; i < end; i++) {
        int g = batch[i];
        if (g != cur) {
            atomicAdd(&sums[cur * FDIM + lane], acc);
            if (lane == 0) atomicAdd(&cnt[cur], (float)count);
            acc = 0.f;
            count = 0;
            cur = g;
        }
        acc += bf2f(h[(long)i * FDIM + lane]);
        count++;
    }
    atomicAdd(&sums[cur * FDIM + lane], acc);
    if (lane == 0) atomicAdd(&cnt[cur], (float)count);
}

// ---------------- head: one wave per graph ----------------

__global__ __launch_bounds__(64) void k_head(const float* __restrict__ sums,
                                             const float* __restrict__ cnt,
                                             const float* __restrict__ W0,
                                             const float* __restrict__ b0,
                                             const float* __restrict__ W1,
                                             const float* __restrict__ b1,
                                             float* __restrict__ out, int OUT) {
    int g = blockIdx.x;
    int lane = threadIdx.x;
    float c = cnt[g];
    if (c < 1.f) c = 1.f;
    float p = sums[g * FDIM + lane] / c;

    float h0 = 0.f, h1 = 0.f, h2 = 0.f, h3 = 0.f;
#pragma unroll
    for (int k = 0; k < FDIM; k += 4) {
        h0 += bcastf(p, k + 0) * W0[(k + 0) * FDIM + lane];
        h1 += bcastf(p, k + 1) * W0[(k + 1) * FDIM + lane];
        h2 += bcastf(p, k + 2) * W0[(k + 2) * FDIM + lane];
        h3 += bcastf(p, k + 3) * W0[(k + 3) * FDIM + lane];
    }
    float hid = b0[lane] + ((h0 + h1) + (h2 + h3));
    for (int o = 0; o < OUT; o++) {
        float part = hid * W1[lane * OUT + o];
#pragma unroll
        for (int m = 32; m >= 1; m >>= 1) part += __shfl_xor(part, m, 64);
        if (lane == 0) out[g * OUT + o] = part + b1[o];
    }
}

extern "C" void kernel_launch(void* const* d_in, const int* in_sizes, int n_in,
                              void* d_out, int out_size, void* d_ws, size_t ws_size,
                              hipStream_t stream) {
    const float* x     = (const float*)d_in[0];
    const int*   ei    = (const int*)d_in[1];
    const int*   batch = (const int*)d_in[2];
    const float* W1r = (const float*)d_in[3];
    const float* b1  = (const float*)d_in[4];
    const float* W1o = (const float*)d_in[5];
    const float* W2r = (const float*)d_in[6];
    const float* b2  = (const float*)d_in[7];
    const float* W2o = (const float*)d_in[8];
    const float* W3r = (const float*)d_in[9];
    const float* b3  = (const float*)d_in[10];
    const float* W3o = (const float*)d_in[11];
    const float* a1  = (const float*)d_in[12];
    const float* a2  = (const float*)d_in[13];
    const float* Wl0 = (const float*)d_in[14];
    const float* bl0 = (const float*)d_in[15];
    const float* Wl1 = (const float*)d_in[16];
    const float* bl1 = (const float*)d_in[17];

    int N = in_sizes[0] / FDIM;
    int E = in_sizes[1] / 2;
    int OUT = in_sizes[17];
    int G = out_size / OUT;

    const int* src = ei;
    const int* dst = ei + E;

    // workspace layout
    char* w = (char*)d_ws;
    int* rowstart = (int*)w;             w += align_up((size_t)(N + 1) * 4);
    int* deg      = (int*)w;             w += align_up((size_t)N * 4);
    int* cursor   = (int*)w;             w += align_up((size_t)N * 4);
    int* bsum     = (int*)w;             w += align_up(1024 * 4);
    int* adj      = (int*)w;             w += align_up((size_t)E * 4 + 256); // +pad for coalesced tail read
    unsigned short* xbf = (unsigned short*)w;  w += align_up((size_t)N * FDIM * 2);
    unsigned short* hb1 = (unsigned short*)w;  w += align_up((size_t)N * FDIM * 2);
    unsigned short* hb2 = (unsigned short*)w;  w += align_up((size_t)N * FDIM * 2);
    unsigned short* hb3 = (unsigned short*)w;  w += align_up((size_t)N * FDIM * 2);
    float* sums   = (float*)w;           w += align_up((size_t)G * FDIM * 4);
    float* cnt    = (float*)w;           w += align_up((size_t)G * 4);

    hipMemsetAsync(deg, 0, (size_t)N * 4, stream);
    hipMemsetAsync(cursor, 0, (size_t)N * 4, stream);
    hipMemsetAsync(sums, 0, (size_t)G * FDIM * 4, stream);
    hipMemsetAsync(cnt, 0, (size_t)G * 4, stream);

    // CSR build
    k_count<<<(E + 255) / 256, 256, 0, stream>>>(dst, deg, E);
    int NB = (N + 1023) / 1024;
    k_scan1<<<NB, 256, 0, stream>>>(deg, bsum, N);
    k_scan2<<<1, 64, 0, stream>>>(bsum, NB, rowstart, N, E);
    k_scan3<<<NB, 256, 0, stream>>>(deg, bsum, rowstart, N);
    k_fill<<<(E + 255) / 256, 256, 0, stream>>>(src, dst, rowstart, cursor, adj, E);

    // x -> bf16
    k_cvt<<<2048, 256, 0, stream>>>(x, xbf, (long)N * FDIM / 4);

    // fused layers (wave per node)
    int layerGrid = 2048;
    k_layer<<<layerGrid, 256, 0, stream>>>(xbf, rowstart, adj, W1r, W1o, b1, a1, hb1, N, 1);
    k_layer<<<layerGrid, 256, 0, stream>>>(hb1, rowstart, adj, W2r, W2o, b2, a2, hb2, N, 1);
    k_layer<<<layerGrid, 256, 0, stream>>>(hb2, rowstart, adj, W3r, W3o, b3, nullptr, hb3, N, 0);

    // mean pool + head
    int poolWaves = (N + POOL_CHUNK - 1) / POOL_CHUNK;
    int poolGrid = (poolWaves + 3) / 4;
    k_pool<<<poolGrid, 256, 0, stream>>>(hb3, batch, sums, cnt, N);
    k_head<<<G, 64, 0, stream>>>(sums, cnt, Wl0, bl0, Wl1, bl1, (float*)d_out, OUT);
}

// Round 10
// 381.743 us; speedup vs baseline: 4.0976x; 1.1880x over previous
//
#include <hip/hip_runtime.h>

#define FDIM 64
#define POOL_CHUNK 64    // nodes per wave in pooling

typedef unsigned int uint32;
typedef __attribute__((ext_vector_type(8))) short bf8v;   // 8 bf16 in 4 VGPRs
typedef __attribute__((ext_vector_type(4))) float f4v;    // 4 fp32

static inline size_t align_up(size_t v) { return (v + 255) & ~(size_t)255; }

__device__ __forceinline__ float bcastf(float v, int l) {
    return __int_as_float(__builtin_amdgcn_readlane(__float_as_int(v), l));
}
__device__ __forceinline__ unsigned short f2bf(float f) {   // RNE
    uint32 u = __float_as_uint(f);
    return (unsigned short)((u + 0x7FFFu + ((u >> 16) & 1u)) >> 16);
}
__device__ __forceinline__ float bf2f(unsigned short s) {
    return __uint_as_float(((uint32)s) << 16);
}

// ---------------- CSR build ----------------

__global__ void k_count(const int* __restrict__ dst, int* __restrict__ deg, int E) {
    int e = blockIdx.x * blockDim.x + threadIdx.x;
    if (e < E) atomicAdd(&deg[dst[e]], 1);
}

__global__ void k_scan1(const int* __restrict__ deg, int* __restrict__ bsum, int n) {
    __shared__ int sh[256];
    int base = blockIdx.x * 1024;
    int t = threadIdx.x;
    int s = 0;
#pragma unroll
    for (int j = 0; j < 4; j++) {
        int i = base + t * 4 + j;
        s += (i < n) ? deg[i] : 0;
    }
    sh[t] = s;
    __syncthreads();
    for (int off = 128; off > 0; off >>= 1) {
        if (t < off) sh[t] += sh[t + off];
        __syncthreads();
    }
    if (t == 0) bsum[blockIdx.x] = sh[0];
}

__global__ void k_scan2(int* __restrict__ bsum, int nb, int* __restrict__ rowstart, int n, int E) {
    if (threadIdx.x == 0) {
        int acc = 0;
        for (int i = 0; i < nb; i++) {
            int v = bsum[i];
            bsum[i] = acc;
            acc += v;
        }
        rowstart[n] = E;
    }
}

__global__ void k_scan3(const int* __restrict__ deg, const int* __restrict__ bsum,
                        int* __restrict__ rowstart, int n) {
    __shared__ int sh[256];
    int base = blockIdx.x * 1024;
    int t = threadIdx.x;
    int v[4];
    int s = 0;
#pragma unroll
    for (int j = 0; j < 4; j++) {
        int i = base + t * 4 + j;
        v[j] = (i < n) ? deg[i] : 0;
        s += v[j];
    }
    sh[t] = s;
    __syncthreads();
    for (int off = 1; off < 256; off <<= 1) {
        int add = (t >= off) ? sh[t - off] : 0;
        __syncthreads();
        sh[t] += add;
        __syncthreads();
    }
    int excl = (t == 0 ? 0 : sh[t - 1]) + bsum[blockIdx.x];
#pragma unroll
    for (int j = 0; j < 4; j++) {
        int i = base + t * 4 + j;
        if (i < n) {
            rowstart[i] = excl;
            excl += v[j];
        }
    }
}

__global__ void k_fill(const int* __restrict__ src, const int* __restrict__ dst,
                       const int* __restrict__ rowstart, int* __restrict__ cursor,
                       int* __restrict__ adj, int E) {
    int e = blockIdx.x * blockDim.x + threadIdx.x;
    if (e < E) {
        int d = dst[e];
        int pos = rowstart[d] + atomicAdd(&cursor[d], 1);
        adj[pos] = src[e];
    }
}

// ---------------- fused layer via MFMA ----------------
// Wave = 16 nodes. A = [agg | x] (K=128 concat), B = [Wr; Wo] bf16 hi/lo in
// LDS (XOR-swizzled). Gather accumulates fp32 directly in A-fragment layout:
// lane (node=l&15, kg=l>>4) owns feats kb*32 + kg*8 + j.  C layout (verified):
// col = lane&15 (out-feat), row = kg*4 + reg (node).

__global__ __launch_bounds__(256) void k_layer(
    const float* __restrict__ Hin, const int* __restrict__ rowstart,
    const int* __restrict__ adj, const float* __restrict__ Wr,
    const float* __restrict__ Wo, const float* __restrict__ bias,
    const float* __restrict__ slope_p, float* __restrict__ Hout,
    int n, int do_prelu)
{
    __shared__ unsigned short wh[64 * 128];   // W_cat hi, [n][k] swizzled
    __shared__ unsigned short wl[64 * 128];   // W_cat lo

    // stage weights: row nn (out-feat), k 0..127 (0-63 Wr, 64-127 Wo)
    for (int e = threadIdx.x; e < 64 * 128; e += 256) {
        int nn = e >> 7;
        int k  = e & 127;
        float v = (k < 64) ? Wr[k * 64 + nn] : Wo[(k - 64) * 64 + nn];
        unsigned short hi = f2bf(v);
        unsigned short lo = f2bf(v - bf2f(hi));
        int boff = nn * 256 + ((k * 2) ^ ((nn & 7) << 4));
        wh[boff >> 1] = hi;
        wl[boff >> 1] = lo;
    }
    __syncthreads();

    int lane = threadIdx.x & 63;
    int l15  = lane & 15;
    int kg   = lane >> 4;
    int wid  = (blockIdx.x * blockDim.x + threadIdx.x) >> 6;
    int nw   = (gridDim.x * blockDim.x) >> 6;
    int ntiles = (n + 15) >> 4;
    float slope = do_prelu ? slope_p[0] : 1.0f;
    float bv0 = bias[l15], bv1 = bias[16 + l15], bv2 = bias[32 + l15], bv3 = bias[48 + l15];

    for (int t = wid; t < ntiles; t += nw) {
        int node = t * 16 + l15;
        bool valid = node < n;
        int s0 = valid ? rowstart[node] : 0;
        int s1 = valid ? rowstart[node + 1] : 0;

        float acc[16];
#pragma unroll
        for (int i = 0; i < 16; i++) acc[i] = 0.f;

        int e = s0;
        for (; e + 2 <= s1; e += 2) {
            long r0 = adj[e], r1 = adj[e + 1];
            const f4v* p0 = (const f4v*)(Hin + (r0 << 6) + (kg << 3));
            const f4v* p1 = (const f4v*)(Hin + (r1 << 6) + (kg << 3));
            f4v a0 = p0[0], b0 = p0[1], c0 = p0[8], d0 = p0[9];
            f4v a1 = p1[0], b1 = p1[1], c1 = p1[8], d1 = p1[9];
#pragma unroll
            for (int j = 0; j < 4; j++) {
                acc[j]      += a0[j] + a1[j];
                acc[4 + j]  += b0[j] + b1[j];
                acc[8 + j]  += c0[j] + c1[j];
                acc[12 + j] += d0[j] + d1[j];
            }
        }
        if (e < s1) {
            long r0 = adj[e];
            const f4v* p0 = (const f4v*)(Hin + (r0 << 6) + (kg << 3));
            f4v a0 = p0[0], b0 = p0[1], c0 = p0[8], d0 = p0[9];
#pragma unroll
            for (int j = 0; j < 4; j++) {
                acc[j]      += a0[j];
                acc[4 + j]  += b0[j];
                acc[8 + j]  += c0[j];
                acc[12 + j] += d0[j];
            }
        }

        // own row (root term)
        float xv[16];
        if (valid) {
            const f4v* p = (const f4v*)(Hin + ((long)node << 6) + (kg << 3));
            f4v a0 = p[0], b0 = p[1], c0 = p[8], d0 = p[9];
#pragma unroll
            for (int j = 0; j < 4; j++) {
                xv[j] = a0[j]; xv[4 + j] = b0[j]; xv[8 + j] = c0[j]; xv[12 + j] = d0[j];
            }
        } else {
#pragma unroll
            for (int i = 0; i < 16; i++) xv[i] = 0.f;
        }

        // build hi/lo A-fragments: kb 0,1 = agg, kb 2,3 = x
        bf8v ah[4], al[4];
#pragma unroll
        for (int kb = 0; kb < 2; kb++) {
#pragma unroll
            for (int j = 0; j < 8; j++) {
                float v = acc[kb * 8 + j];
                unsigned short h = f2bf(v);
                ah[kb][j] = (short)h;
                al[kb][j] = (short)f2bf(v - bf2f(h));
            }
        }
#pragma unroll
        for (int kb = 0; kb < 2; kb++) {
#pragma unroll
            for (int j = 0; j < 8; j++) {
                float v = xv[kb * 8 + j];
                unsigned short h = f2bf(v);
                ah[2 + kb][j] = (short)h;
                al[2 + kb][j] = (short)f2bf(v - bf2f(h));
            }
        }

        f4v C[4];
        C[0] = (f4v){bv0, bv0, bv0, bv0};
        C[1] = (f4v){bv1, bv1, bv1, bv1};
        C[2] = (f4v){bv2, bv2, bv2, bv2};
        C[3] = (f4v){bv3, bv3, bv3, bv3};

#pragma unroll
        for (int kb = 0; kb < 4; kb++) {
#pragma unroll
            for (int nt = 0; nt < 4; nt++) {
                int row = nt * 16 + l15;
                int boff = row * 256 + (((kb * 32 + kg * 8) * 2) ^ ((l15 & 7) << 4));
                bf8v bh = *(const bf8v*)((const char*)wh + boff);
                bf8v bl = *(const bf8v*)((const char*)wl + boff);
                C[nt] = __builtin_amdgcn_mfma_f32_16x16x32_bf16(ah[kb], bh, C[nt], 0, 0, 0);
                C[nt] = __builtin_amdgcn_mfma_f32_16x16x32_bf16(al[kb], bh, C[nt], 0, 0, 0);
                C[nt] = __builtin_amdgcn_mfma_f32_16x16x32_bf16(ah[kb], bl, C[nt], 0, 0, 0);
            }
        }

        // epilogue: C row = node (kg*4 + r), col = out-feat (nt*16 + l15)
#pragma unroll
        for (int r = 0; r < 4; r++) {
            int onode = t * 16 + kg * 4 + r;
            if (onode < n) {
#pragma unroll
                for (int nt = 0; nt < 4; nt++) {
                    float v = C[nt][r];
                    v = v >= 0.f ? v : slope * v;
                    Hout[((long)onode << 6) + nt * 16 + l15] = v;
                }
            }
        }
    }
}

// ---------------- global mean pool (fp32, sorted batch) ----------------

__global__ __launch_bounds__(256) void k_pool(const float* __restrict__ h,
                                              const int* __restrict__ batch,
                                              float* __restrict__ sums,
                                              float* __restrict__ cnt, int n) {
    int wave = (blockIdx.x * 256 + threadIdx.x) >> 6;
    int lane = threadIdx.x & 63;
    int start = wave * POOL_CHUNK;
    if (start >= n) return;
    int end = start + POOL_CHUNK;
    if (end > n) end = n;
    int cur = batch[start];
    float acc = 0.f;
    int count = 0;
#pragma unroll 4
    for (int i = start; i < end; i++) {
        int g = batch[i];
        if (g != cur) {
            atomicAdd(&sums[cur * FDIM + lane], acc);
            if (lane == 0) atomicAdd(&cnt[cur], (float)count);
            acc = 0.f;
            count = 0;
            cur = g;
        }
        acc += h[(long)i * FDIM + lane];
        count++;
    }
    atomicAdd(&sums[cur * FDIM + lane], acc);
    if (lane == 0) atomicAdd(&cnt[cur], (float)count);
}

// ---------------- head: one wave per graph ----------------

__global__ __launch_bounds__(64) void k_head(const float* __restrict__ sums,
                                             const float* __restrict__ cnt,
                                             const float* __restrict__ W0,
                                             const float* __restrict__ b0,
                                             const float* __restrict__ W1,
                                             const float* __restrict__ b1,
                                             float* __restrict__ out, int OUT) {
    int g = blockIdx.x;
    int lane = threadIdx.x;
    float c = cnt[g];
    if (c < 1.f) c = 1.f;
    float p = sums[g * FDIM + lane] / c;

    float h0 = 0.f, h1 = 0.f, h2 = 0.f, h3 = 0.f;
#pragma unroll
    for (int k = 0; k < FDIM; k += 4) {
        h0 += bcastf(p, k + 0) * W0[(k + 0) * FDIM + lane];
        h1 += bcastf(p, k + 1) * W0[(k + 1) * FDIM + lane];
        h2 += bcastf(p, k + 2) * W0[(k + 2) * FDIM + lane];
        h3 += bcastf(p, k + 3) * W0[(k + 3) * FDIM + lane];
    }
    float hid = b0[lane] + ((h0 + h1) + (h2 + h3));
    for (int o = 0; o < OUT; o++) {
        float part = hid * W1[lane * OUT + o];
#pragma unroll
        for (int m = 32; m >= 1; m >>= 1) part += __shfl_xor(part, m, 64);
        if (lane == 0) out[g * OUT + o] = part + b1[o];
    }
}

extern "C" void kernel_launch(void* const* d_in, const int* in_sizes, int n_in,
                              void* d_out, int out_size, void* d_ws, size_t ws_size,
                              hipStream_t stream) {
    const float* x     = (const float*)d_in[0];
    const int*   ei    = (const int*)d_in[1];
    const int*   batch = (const int*)d_in[2];
    const float* W1r = (const float*)d_in[3];
    const float* b1  = (const float*)d_in[4];
    const float* W1o = (const float*)d_in[5];
    const float* W2r = (const float*)d_in[6];
    const float* b2  = (const float*)d_in[7];
    const float* W2o = (const float*)d_in[8];
    const float* W3r = (const float*)d_in[9];
    const float* b3  = (const float*)d_in[10];
    const float* W3o = (const float*)d_in[11];
    const float* a1  = (const float*)d_in[12];
    const float* a2  = (const float*)d_in[13];
    const float* Wl0 = (const float*)d_in[14];
    const float* bl0 = (const float*)d_in[15];
    const float* Wl1 = (const float*)d_in[16];
    const float* bl1 = (const float*)d_in[17];

    int N = in_sizes[0] / FDIM;
    int E = in_sizes[1] / 2;
    int OUT = in_sizes[17];
    int G = out_size / OUT;

    const int* src = ei;
    const int* dst = ei + E;

    // workspace layout
    char* w = (char*)d_ws;
    int* rowstart = (int*)w;            w += align_up((size_t)(N + 1) * 4);
    int* deg      = (int*)w;            w += align_up((size_t)N * 4);
    int* cursor   = (int*)w;            w += align_up((size_t)N * 4);
    int* bsum     = (int*)w;            w += align_up(1024 * 4);
    int* adj      = (int*)w;            w += align_up((size_t)E * 4 + 256);
    float* h1     = (float*)w;          w += align_up((size_t)N * FDIM * 4);
    float* h2     = (float*)w;          w += align_up((size_t)N * FDIM * 4);
    float* sums   = (float*)w;          w += align_up((size_t)G * FDIM * 4);
    float* cnt    = (float*)w;          w += align_up((size_t)G * 4);

    hipMemsetAsync(deg, 0, (size_t)N * 4, stream);
    hipMemsetAsync(cursor, 0, (size_t)N * 4, stream);
    hipMemsetAsync(sums, 0, (size_t)G * FDIM * 4, stream);
    hipMemsetAsync(cnt, 0, (size_t)G * 4, stream);

    // CSR build
    k_count<<<(E + 255) / 256, 256, 0, stream>>>(dst, deg, E);
    int NB = (N + 1023) / 1024;
    k_scan1<<<NB, 256, 0, stream>>>(deg, bsum, N);
    k_scan2<<<1, 64, 0, stream>>>(bsum, NB, rowstart, N, E);
    k_scan3<<<NB, 256, 0, stream>>>(deg, bsum, rowstart, N);
    k_fill<<<(E + 255) / 256, 256, 0, stream>>>(src, dst, rowstart, cursor, adj, E);

    // MFMA fused layers (wave = 16 nodes; 1280 blocks * 4 waves)
    int layerGrid = 1280;
    k_layer<<<layerGrid, 256, 0, stream>>>(x,  rowstart, adj, W1r, W1o, b1, a1, h1, N, 1);
    k_layer<<<layerGrid, 256, 0, stream>>>(h1, rowstart, adj, W2r, W2o, b2, a2, h2, N, 1);
    k_layer<<<layerGrid, 256, 0, stream>>>(h2, rowstart, adj, W3r, W3o, b3, nullptr, h1, N, 0);

    // mean pool + head
    int poolWaves = (N + POOL_CHUNK - 1) / POOL_CHUNK;
    int poolGrid = (poolWaves + 3) / 4;
    k_pool<<<poolGrid, 256, 0, stream>>>(h1, batch, sums, cnt, N);
    k_head<<<G, 64, 0, stream>>>(sums, cnt, Wl0, bl0, Wl1, bl1, (float*)d_out, OUT);
}